// Round 15
// baseline (109.473 us; speedup 1.0000x reference)
//
#include <hip/hip_runtime.h>
#include <stdint.h>

typedef unsigned short ushort_t;
typedef __bf16 bf16x4 __attribute__((ext_vector_type(4)));
typedef __bf16 bf16x8 __attribute__((ext_vector_type(8)));
typedef float f32x4 __attribute__((ext_vector_type(4)));
typedef float f32x16 __attribute__((ext_vector_type(16)));
typedef unsigned short us8 __attribute__((ext_vector_type(8)));
typedef unsigned short us4v __attribute__((ext_vector_type(4)));

__device__ __forceinline__ float bf2f(ushort_t u) {
  union { uint32_t u; float f; } v; v.u = ((uint32_t)u) << 16; return v.f;
}
__device__ __forceinline__ ushort_t f2bf(float f) {
  union { float f; uint32_t u; } v; v.f = f;
  uint32_t u = v.u;
  uint32_t r = (u + 0x7FFFu + ((u >> 16) & 1u)) >> 16;  // RNE
  return (ushort_t)r;
}
// hardware packed bf16 convert (RNE): dst = {lo: bf16(a), hi: bf16(b)}
__device__ __forceinline__ uint32_t cvtpk(float a, float b) {
  uint32_t r;
  asm("v_cvt_pk_bf16_f32 %0, %1, %2" : "=v"(r) : "v"(a), "v"(b));
  return r;
}
__device__ __forceinline__ void gload_lds16(const void* g, void* l) {
  __builtin_amdgcn_global_load_lds(
      (const __attribute__((address_space(1))) void*)g,
      (__attribute__((address_space(3))) void*)l, 16, 0, 0);
}
// ds_read_b64_tr_b16 (cross-lane transpose): 16-lane group, lane reads its
// own qword at base+(l&15)*8; delivers column (l&15) of the [4kv][16d] subtile.
__device__ __forceinline__ void tr2(const ushort_t* p, bf16x4& lo, bf16x4& hi) {
  asm volatile("ds_read_b64_tr_b16 %0, %2\n\t"
               "ds_read_b64_tr_b16 %1, %2 offset:128"
               : "=&v"(lo), "=&v"(hi)
               : "v"((const __attribute__((address_space(3))) ushort_t*)p));
}

template <typename T> __device__ __forceinline__ T to_out(float f);
template <> __device__ __forceinline__ ushort_t to_out<ushort_t>(float f) { return f2bf(f); }
template <> __device__ __forceinline__ float to_out<float>(float f) { return f; }

#define SCQ 0.1803368801111204f   /* 0.125 * log2(e) */

// ---------------------------------------------------------------------------
// fp32 -> bf16 convert, three inputs, static block partition
// ---------------------------------------------------------------------------
__global__ void f2b3_kernel(const float* __restrict__ a, ushort_t* __restrict__ ao,
                            const float* __restrict__ b, ushort_t* __restrict__ bo,
                            const float* __restrict__ c, ushort_t* __restrict__ co) {
  int blk = blockIdx.x;
  const float* src; ushort_t* dst; int n4, b0, nb;
  if (blk < 1024)      { src = a; dst = ao; n4 = 1048576; b0 = blk;        nb = 1024; }
  else if (blk < 1792) { src = b; dst = bo; n4 = 786432;  b0 = blk - 1024; nb = 768; }
  else                 { src = c; dst = co; n4 = 262144;  b0 = blk - 1792; nb = 256; }
  for (int i = b0 * 256 + threadIdx.x; i < n4; i += nb * 256) {
    float4 v = ((const float4*)src)[i];
    us4v o;
    o[0] = f2bf(v.x); o[1] = f2bf(v.y); o[2] = f2bf(v.z); o[3] = f2bf(v.w);
    ((us4v*)dst)[i] = o;
  }
}

// ---------------------------------------------------------------------------
// GEMM: C[M][N] = A[M][K] @ W[N][K]^T (+bias), bf16 in, fp32 accum, OT out.
// SCALEQ: multiply output cols < 1024 by SCQ (Q-prescale for attn).
// T1 XCD swizzle: bijective blockIdx remap (nwg % 8 == 0).
// ---------------------------------------------------------------------------
template<bool BIAS, typename OT, bool SCALEQ>
__global__ __launch_bounds__(256, 2) void gemm_bt(
    const ushort_t* __restrict__ A, const ushort_t* __restrict__ W,
    const float* __restrict__ bias, OT* __restrict__ C,
    int M, int N, int K)
{
  __shared__ ushort_t As[128 * 64];
  __shared__ ushort_t Bs[128 * 64];
  const int t = threadIdx.x;
  const int w = t >> 6, lane = t & 63;
  const int lg = lane >> 4, lc = lane & 15;

  const int NX = N >> 7;
  const int nwg = gridDim.x;
  const int o = blockIdx.x;
  const int id = (o & 7) * (nwg >> 3) + (o >> 3);
  const int rowbase = (id / NX) * 128;
  const int colbase = (id % NX) * 128;
  const int wr = (w >> 1) * 64, wc = (w & 1) * 64;

  f32x4 acc[4][4] = {};
  const int nkt = K >> 6;

  for (int kt = 0; kt < nkt; ++kt) {
#pragma unroll
    for (int i = 0; i < 4; ++i) {
      int off = (i * 256 + t) * 16;
      int row = off >> 7;
      int cb  = off & 127;
      int ec  = cb ^ ((row & 7) << 4);
      gload_lds16(A + (size_t)(rowbase + row) * K + kt * 64 + (ec >> 1),
                  (char*)As + off);
      gload_lds16(W + (size_t)(colbase + row) * K + kt * 64 + (ec >> 1),
                  (char*)Bs + off);
    }
    __syncthreads();
#pragma unroll
    for (int kk = 0; kk < 2; ++kk) {
      bf16x8 af[4], bf[4];
#pragma unroll
      for (int m = 0; m < 4; ++m) {
        int row = wr + m * 16 + lc;
        int kb  = (lg * 16 + kk * 64) ^ ((row & 7) << 4);
        af[m] = *(const bf16x8*)((const char*)As + row * 128 + kb);
        int col = wc + m * 16 + lc;
        int kb2 = (lg * 16 + kk * 64) ^ ((col & 7) << 4);
        bf[m] = *(const bf16x8*)((const char*)Bs + col * 128 + kb2);
      }
#pragma unroll
      for (int m = 0; m < 4; ++m)
#pragma unroll
        for (int n = 0; n < 4; ++n)
          acc[m][n] = __builtin_amdgcn_mfma_f32_16x16x32_bf16(af[m], bf[n],
                                                              acc[m][n], 0, 0, 0);
    }
    __syncthreads();
  }

#pragma unroll
  for (int m = 0; m < 4; ++m) {
    int r0 = rowbase + wr + m * 16 + lg * 4;
#pragma unroll
    for (int n = 0; n < 4; ++n) {
      int c0 = colbase + wc + n * 16 + lc;
      float bv = 0.f;
      if (BIAS) bv = bias[c0];
      float qs = 1.f;
      if (SCALEQ) qs = (c0 < 1024) ? SCQ : 1.f;
#pragma unroll
      for (int j = 0; j < 4; ++j)
        C[(size_t)(r0 + j) * N + c0] = to_out<OT>(acc[m][n][j] * qs + bv);
    }
  }
}

// ---------------------------------------------------------------------------
// Flash attention v12: DS-traffic halved. 4 waves (256 thr), q-tile 256 =
// 64 q-rows/wave in TWO q-groups (A: w*64+l31, B: +32); each wave's full
// K/V tile reads now serve 2x the q-work (kernel was LDS-BW-bound at 8x32).
// KV-split(2), 16 iters kv64, max-free softmax (Q pre-scaled), cvt_pk pack,
// permlane32_swap, tr_read V, VALU tree l-sum (deferred cross-half).
// Partials unnormalized bf16 + l; merged by merge_kernel.
// ---------------------------------------------------------------------------
__global__ __launch_bounds__(256, 2) void attn_fwd(
    const ushort_t* __restrict__ qkv, ushort_t* __restrict__ o1,
    ushort_t* __restrict__ o2, float* __restrict__ lbuf)
{
  __shared__ ushort_t Ks[2][64 * 64];
  __shared__ ushort_t Vs[2][64 * 64];

  const int t = threadIdx.x, w = t >> 6, lane = t & 63;
  const int l31 = lane & 31, hi = lane >> 5;
  const int lc = lane & 15;
  const int m16 = (lane >> 4) & 1;

  // bijective decode: xcd = d&7, qt = (d>>3)&7, bhs = xcd*8 + (d>>6)
  const int d = blockIdx.x;
  const int qt = (d >> 3) & 7;
  const int bhs = (d & 7) * 8 + (d >> 6);
  const int bh = bhs >> 1, split = bhs & 1;
  const int b = bh >> 4, h = bh & 15;

  const ushort_t* Qg = qkv + (size_t)(b * 2048) * 3072 + h * 64;
  const ushort_t* Kg = Qg + 1024 + (size_t)split * 1024 * 3072;
  const ushort_t* Vg = Qg + 2048 + (size_t)split * 1024 * 3072;

  // K stage: 2 x 16B gload per thread (256 thr cover 64x64 bf16)
  auto stage_k = [&](ushort_t* Kd, int kt) {
#pragma unroll
    for (int i = 0; i < 2; ++i) {
      int off = (i * 256 + t) * 16;
      int row = off >> 7;
      int cb  = off & 127;
      int ec  = cb ^ ((row & 7) << 4);
      gload_lds16(Kg + (size_t)(kt * 64 + row) * 3072 + (ec >> 1),
                  (char*)Kd + off);
    }
  };
  // V stage dest (verified subtiled layout [d16][kv4][4][16]), 2 per thread
  int vr[2], vc0[2], vdst[2];
#pragma unroll
  for (int i = 0; i < 2; ++i) {
    int u = i * 256 + t;
    vr[i]  = u >> 3;
    vc0[i] = (u & 7) * 8;
    vdst[i] = (vc0[i] >> 4) * 2048 + (vr[i] >> 2) * 128 + (vr[i] & 3) * 32 +
              (vc0[i] & 8) * 2;
  }

  // ---- Q fragments, two groups: A rows w*64+l31, B rows +32 ----
  const ushort_t* qpA = Qg + (size_t)(qt * 256 + w * 64 + l31) * 3072;
  const ushort_t* qpB = qpA + (size_t)32 * 3072;
  bf16x8 qfA[4], qfB[4];
#pragma unroll
  for (int kk = 0; kk < 4; ++kk) {
    qfA[kk] = *(const bf16x8*)(qpA + kk * 16 + hi * 8);
    qfB[kk] = *(const bf16x8*)(qpB + kk * 16 + hi * 8);
  }

  // ---- prologue staging ----
  stage_k(Ks[0], 0);
#pragma unroll
  for (int i = 0; i < 2; ++i) {
    us8 v = *(const us8*)(Vg + (size_t)vr[i] * 3072 + vc0[i]);
    *(us8*)((char*)Vs[0] + vdst[i]) = v;
  }
  __syncthreads();

  f32x16 oA0 = {}, oA1 = {}, oB0 = {}, oB1 = {};
  float lA = 0.f, lB = 0.f;

  int cur = 0;
  for (int kt = 0; kt < 16; ++kt) {
    // ---- issue next tile's loads early ----
    us8 vnext[2];
    if (kt < 15) {
      stage_k(Ks[cur ^ 1], kt + 1);
#pragma unroll
      for (int i = 0; i < 2; ++i)
        vnext[i] = *(const us8*)(Vg + (size_t)((kt + 1) * 64 + vr[i]) * 3072 + vc0[i]);
    }

    // ---- S^T = K @ Q'^T, both q-groups (K fragments read once) ----
    const ushort_t* Kc = Ks[cur];
    f32x16 sA0 = {}, sA1 = {}, sB0 = {}, sB1 = {};
    __builtin_amdgcn_s_setprio(1);
#pragma unroll
    for (int kk = 0; kk < 4; ++kk) {
      int cbyte = (kk * 32 + hi * 16);
      int r0 = l31, r1 = 32 + l31;
      bf16x8 kf0 = *(const bf16x8*)((const char*)Kc + r0 * 128 +
                                    (cbyte ^ ((r0 & 7) << 4)));
      bf16x8 kf1 = *(const bf16x8*)((const char*)Kc + r1 * 128 +
                                    (cbyte ^ ((r1 & 7) << 4)));
      sA0 = __builtin_amdgcn_mfma_f32_32x32x16_bf16(kf0, qfA[kk], sA0, 0, 0, 0);
      sA1 = __builtin_amdgcn_mfma_f32_32x32x16_bf16(kf1, qfA[kk], sA1, 0, 0, 0);
      sB0 = __builtin_amdgcn_mfma_f32_32x32x16_bf16(kf0, qfB[kk], sB0, 0, 0, 0);
      sB1 = __builtin_amdgcn_mfma_f32_32x32x16_bf16(kf1, qfB[kk], sB1, 0, 0, 0);
    }
    __builtin_amdgcn_s_setprio(0);

    // ---- issue V tr-reads now: DS latency hides under softmax VALU ----
    const ushort_t* Vc = Vs[cur];
    bf16x8 vf[4][2];
#pragma unroll
    for (int ks = 0; ks < 4; ++ks)
#pragma unroll
      for (int nd = 0; nd < 2; ++nd) {
        bf16x4 lo, hh;
        tr2(Vc + (nd * 2 + m16) * 1024 + (4 * ks + 2 * hi) * 64 + lc * 4, lo, hh);
        vf[ks][nd] = __builtin_shufflevector(lo, hh, 0, 1, 2, 3, 4, 5, 6, 7);
      }

    // ---- max-free softmax + pack, group A ----
    bf16x8 paA[4], paB[4];
    {
#pragma unroll
      for (int i = 0; i < 16; ++i) {
        sA0[i] = __builtin_amdgcn_exp2f(sA0[i]);
        sA1[i] = __builtin_amdgcn_exp2f(sA1[i]);
      }
      lA += ((((sA0[0] + sA0[1]) + (sA0[2] + sA0[3])) +
              ((sA0[4] + sA0[5]) + (sA0[6] + sA0[7]))) +
             (((sA0[8] + sA0[9]) + (sA0[10] + sA0[11])) +
              ((sA0[12] + sA0[13]) + (sA0[14] + sA0[15])))) +
            ((((sA1[0] + sA1[1]) + (sA1[2] + sA1[3])) +
              ((sA1[4] + sA1[5]) + (sA1[6] + sA1[7]))) +
             (((sA1[8] + sA1[9]) + (sA1[10] + sA1[11])) +
              ((sA1[12] + sA1[13]) + (sA1[14] + sA1[15]))));
      uint32_t pk0[8], pk1[8];
#pragma unroll
      for (int j = 0; j < 8; ++j) {
        pk0[j] = cvtpk(sA0[2 * j], sA0[2 * j + 1]);
        pk1[j] = cvtpk(sA1[2 * j], sA1[2 * j + 1]);
      }
#pragma unroll
      for (int ks = 0; ks < 4; ++ks) {
        int j0 = 4 * (ks & 1);
        uint32_t x0 = (ks < 2) ? pk0[j0]     : pk1[j0];
        uint32_t x1 = (ks < 2) ? pk0[j0 + 1] : pk1[j0 + 1];
        uint32_t y0 = (ks < 2) ? pk0[j0 + 2] : pk1[j0 + 2];
        uint32_t y1 = (ks < 2) ? pk0[j0 + 3] : pk1[j0 + 3];
        asm volatile("v_permlane32_swap_b32 %0, %1" : "+v"(x0), "+v"(y0));
        asm volatile("v_permlane32_swap_b32 %0, %1" : "+v"(x1), "+v"(y1));
        union { uint32_t du[4]; bf16x8 v; } U;
        U.du[0] = x0; U.du[1] = x1; U.du[2] = y0; U.du[3] = y1;
        paA[ks] = U.v;
      }
    }
    // ---- group B ----
    {
#pragma unroll
      for (int i = 0; i < 16; ++i) {
        sB0[i] = __builtin_amdgcn_exp2f(sB0[i]);
        sB1[i] = __builtin_amdgcn_exp2f(sB1[i]);
      }
      lB += ((((sB0[0] + sB0[1]) + (sB0[2] + sB0[3])) +
              ((sB0[4] + sB0[5]) + (sB0[6] + sB0[7]))) +
             (((sB0[8] + sB0[9]) + (sB0[10] + sB0[11])) +
              ((sB0[12] + sB0[13]) + (sB0[14] + sB0[15])))) +
            ((((sB1[0] + sB1[1]) + (sB1[2] + sB1[3])) +
              ((sB1[4] + sB1[5]) + (sB1[6] + sB1[7]))) +
             (((sB1[8] + sB1[9]) + (sB1[10] + sB1[11])) +
              ((sB1[12] + sB1[13]) + (sB1[14] + sB1[15]))));
      uint32_t pk0[8], pk1[8];
#pragma unroll
      for (int j = 0; j < 8; ++j) {
        pk0[j] = cvtpk(sB0[2 * j], sB0[2 * j + 1]);
        pk1[j] = cvtpk(sB1[2 * j], sB1[2 * j + 1]);
      }
#pragma unroll
      for (int ks = 0; ks < 4; ++ks) {
        int j0 = 4 * (ks & 1);
        uint32_t x0 = (ks < 2) ? pk0[j0]     : pk1[j0];
        uint32_t x1 = (ks < 2) ? pk0[j0 + 1] : pk1[j0 + 1];
        uint32_t y0 = (ks < 2) ? pk0[j0 + 2] : pk1[j0 + 2];
        uint32_t y1 = (ks < 2) ? pk0[j0 + 3] : pk1[j0 + 3];
        asm volatile("v_permlane32_swap_b32 %0, %1" : "+v"(x0), "+v"(y0));
        asm volatile("v_permlane32_swap_b32 %0, %1" : "+v"(x1), "+v"(y1));
        union { uint32_t du[4]; bf16x8 v; } U;
        U.du[0] = x0; U.du[1] = x1; U.du[2] = y0; U.du[3] = y1;
        paB[ks] = U.v;
      }
    }

    // ---- write next V tile (vmcnt wait hidden under QK+softmax) ----
    if (kt < 15) {
#pragma unroll
      for (int i = 0; i < 2; ++i)
        *(us8*)((char*)Vs[cur ^ 1] + vdst[i]) = vnext[i];
    }

    asm volatile("s_waitcnt lgkmcnt(0)" ::: "memory");  // rule #18
    __builtin_amdgcn_sched_barrier(0);
    __builtin_amdgcn_s_setprio(1);
#pragma unroll
    for (int ks = 0; ks < 4; ++ks) {
      oA0 = __builtin_amdgcn_mfma_f32_32x32x16_bf16(paA[ks], vf[ks][0], oA0, 0, 0, 0);
      oA1 = __builtin_amdgcn_mfma_f32_32x32x16_bf16(paA[ks], vf[ks][1], oA1, 0, 0, 0);
      oB0 = __builtin_amdgcn_mfma_f32_32x32x16_bf16(paB[ks], vf[ks][0], oB0, 0, 0, 0);
      oB1 = __builtin_amdgcn_mfma_f32_32x32x16_bf16(paB[ks], vf[ks][1], oB1, 0, 0, 0);
    }
    __builtin_amdgcn_s_setprio(0);

    __syncthreads();   // drains staging; protects double buffers
    cur ^= 1;
  }

  // ---- deferred cross-half l reduce ----
  lA += __shfl_xor(lA, 32);
  lB += __shfl_xor(lB, 32);

  // ---- epilogue: unnormalized partial O + row-sums ----
  ushort_t* op = split ? o2 : o1;
  const int q0 = qt * 256 + w * 64;
#pragma unroll
  for (int r = 0; r < 16; ++r) {
    int crow = (r & 3) + 8 * (r >> 2) + 4 * hi;
    size_t baseA = ((size_t)(b * 2048 + q0 + crow)) * 1024 + h * 64 + l31;
    size_t baseB = baseA + (size_t)32 * 1024;
    op[baseA]      = f2bf(oA0[r]);
    op[baseA + 32] = f2bf(oA1[r]);
    op[baseB]      = f2bf(oB0[r]);
    op[baseB + 32] = f2bf(oB1[r]);
  }
  if (hi == 0) {
    lbuf[(size_t)split * 65536 + (size_t)(b * 2048 + q0 + l31) * 16 + h] = lA;
    lbuf[(size_t)split * 65536 + (size_t)(b * 2048 + q0 + 32 + l31) * 16 + h] = lB;
  }
}

// ---------------------------------------------------------------------------
// merge: o1 = (o1 + o2) / (l1 + l2), in-place (max-free partials).
// ---------------------------------------------------------------------------
__global__ void merge_kernel(ushort_t* __restrict__ o1,
                             const ushort_t* __restrict__ o2,
                             const float* __restrict__ lbuf) {
  int i = blockIdx.x * blockDim.x + threadIdx.x;
  int row = i >> 7;
  int col = (i & 127) * 8;
  int h = col >> 6;
  float l1 = lbuf[(size_t)row * 16 + h];
  float l2 = lbuf[65536 + (size_t)row * 16 + h];
  float inv = 1.f / (l1 + l2);
  us8 v1 = ((const us8*)o1)[i];
  us8 v2 = ((const us8*)o2)[i];
  us8 o;
#pragma unroll
  for (int j = 0; j < 8; ++j)
    o[j] = f2bf((bf2f(v1[j]) + bf2f(v2[j])) * inv);
  ((us8*)o1)[i] = o;
}

// ---------------------------------------------------------------------------
extern "C" void kernel_launch(void* const* d_in, const int* in_sizes, int n_in,
                              void* d_out, int out_size, void* d_ws, size_t ws_size,
                              hipStream_t stream) {
  const float* x     = (const float*)d_in[0];   // [2,2048,1024] fp32
  const float* Wqkv  = (const float*)d_in[1];   // [3072,1024] fp32
  const float* Wproj = (const float*)d_in[2];   // [1024,1024] fp32
  const float* bproj = (const float*)d_in[3];   // [1024] fp32
  float* out = (float*)d_out;                   // [4096,1024] fp32

  ushort_t* qkv   = (ushort_t*)d_ws;                    // [4096,3072] bf16
  ushort_t* o1    = qkv   + (size_t)4096 * 3072;        // [4096,1024] bf16 (O1/merged)
  ushort_t* xb    = o1    + (size_t)4096 * 1024;        // [4096,1024] bf16 (x, then O2)
  ushort_t* wqb   = xb    + (size_t)4096 * 1024;        // [3072,1024] bf16
  ushort_t* wpb   = wqb   + (size_t)3072 * 1024;        // [1024,1024] bf16
  float*    lbuf  = (float*)(wpb + (size_t)1024 * 1024); // [2][4096][16] float

  dim3 blk(256);
  f2b3_kernel<<<2048, blk, 0, stream>>>(x, xb, Wqkv, wqb, Wproj, wpb);

  gemm_bt<false, ushort_t, true><<<768, blk, 0, stream>>>(
      xb, wqb, nullptr, qkv, 4096, 3072, 1024);
  attn_fwd<<<dim3(512), dim3(256), 0, stream>>>(qkv, o1, xb, lbuf);
  merge_kernel<<<2048, blk, 0, stream>>>(o1, xb, lbuf);
  gemm_bt<true, float, false><<<256, blk, 0, stream>>>(
      o1, wpb, bproj, out, 4096, 1024, 1024);
}